// Round 12
// baseline (533.777 us; speedup 1.0000x reference)
//
#include <hip/hip_runtime.h>

#define D 128
#define K_ORDER 6
#define NB_SHIFT 9           // bucket = dst >> 9 (512 nodes/bucket)
#define CPT 8                // edges per thread in binning passes
#define BPAD 4096            // per-bucket padded slack (>= 512*7 + 8)

typedef __attribute__((ext_vector_type(8))) short short8;
typedef __attribute__((ext_vector_type(4))) float f32x4;
typedef __attribute__((ext_vector_type(4))) unsigned uint4v;

__device__ __forceinline__ float silu_f(float x) {
    return x / (1.0f + __expf(-x));
}

__device__ __forceinline__ unsigned pack_bf2(float lo, float hi) {
    unsigned ul = __float_as_uint(lo);
    unsigned uh = __float_as_uint(hi);
    ul = (ul + 0x7fffu + ((ul >> 16) & 1u)) >> 16;          // RNE
    uh = (uh + 0x7fffu + ((uh >> 16) & 1u)) & 0xffff0000u;  // RNE, keep high
    return uh | ul;
}

__device__ __forceinline__ unsigned short bf16_of(float f) {
    unsigned u = __float_as_uint(f);
    u = (u + 0x7fffu + ((u >> 16) & 1u)) >> 16;
    return (unsigned short)u;
}

// ---------------- CSR build (no global atomics on per-node arrays) ----------

__global__ __launch_bounds__(256) void bucket_hist_kernel(
        const int* __restrict__ dst, int* __restrict__ bucket_cnt, int e, int nb) {
    __shared__ int hist[256];
    for (int i = threadIdx.x; i < 256; i += 256) hist[i] = 0;
    __syncthreads();
    int i0 = blockIdx.x * (256 * CPT) + threadIdx.x;
    #pragma unroll
    for (int k = 0; k < CPT; ++k) {
        int idx = i0 + k * 256;
        if (idx < e) atomicAdd(&hist[dst[idx] >> NB_SHIFT], 1);
    }
    __syncthreads();
    for (int i = threadIdx.x; i < nb; i += 256) {
        int h = hist[i];
        if (h) atomicAdd(&bucket_cnt[i], h);
    }
}

__global__ __launch_bounds__(256) void scan_buckets_kernel(
        const int* __restrict__ bucket_cnt, int* __restrict__ bucket_base,
        int* __restrict__ bin_cur, int nb) {
    __shared__ int lds[256];
    int v = (threadIdx.x < (unsigned)nb) ? bucket_cnt[threadIdx.x] : 0;
    lds[threadIdx.x] = v;
    __syncthreads();
    #pragma unroll
    for (int off = 1; off < 256; off <<= 1) {
        int t = (threadIdx.x >= (unsigned)off) ? lds[threadIdx.x - off] : 0;
        __syncthreads();
        lds[threadIdx.x] += t;
        __syncthreads();
    }
    if (threadIdx.x < (unsigned)nb) {
        int b = lds[threadIdx.x] - v;
        bucket_base[threadIdx.x] = b;
        bin_cur[threadIdx.x] = b;
    }
}

__global__ __launch_bounds__(256) void bin_edges_kernel(
        const int* __restrict__ src, const int* __restrict__ dst,
        int* __restrict__ bin_cur, unsigned* __restrict__ binned, int e, int nb) {
    __shared__ int hist[256];
    __shared__ int base[256];
    for (int i = threadIdx.x; i < 256; i += 256) hist[i] = 0;
    __syncthreads();

    int e0 = blockIdx.x * (256 * CPT) + threadIdx.x;
    int myb[CPT], myoff[CPT];
    unsigned mypk[CPT];
    #pragma unroll
    for (int k = 0; k < CPT; ++k) {
        int idx = e0 + k * 256;
        bool ok = idx < e;
        int d = ok ? dst[idx] : 0;
        int s = ok ? src[idx] : 0;
        int b = d >> NB_SHIFT;
        int off = ok ? atomicAdd(&hist[b], 1) : 0;
        myb[k] = b; myoff[k] = off;
        mypk[k] = ((unsigned)s << NB_SHIFT) | (unsigned)(d & ((1 << NB_SHIFT) - 1));
    }
    __syncthreads();
    for (int i = threadIdx.x; i < nb; i += 256) {
        int h = hist[i];
        base[i] = h ? atomicAdd(&bin_cur[i], h) : 0;
    }
    __syncthreads();
    #pragma unroll
    for (int k = 0; k < CPT; ++k) {
        int idx = e0 + k * 256;
        if (idx < e)
            binned[(size_t)base[myb[k]] + myoff[k]] = mypk[k];
    }
}

// Per-bucket CSR finalize with 8-padding: each row's edge list is padded to a
// multiple of 8 with dummy src = n (zero feature row). row_start is 8-aligned.
__global__ __launch_bounds__(512) void bucket_csr_kernel(
        const unsigned* __restrict__ binned, const int* __restrict__ bucket_base,
        int* __restrict__ row_start, int* __restrict__ degv,
        int* __restrict__ ssrc, int n, int e, int nb) {
    __shared__ int hist[512];
    __shared__ int pfx[512];
    const int b = blockIdx.x;
    const int node0 = b << NB_SHIFT;
    const int beg = bucket_base[b];
    const int end = (b + 1 < nb) ? bucket_base[b + 1] : e;
    const int pbeg = ((beg + 7) & ~7) + b * BPAD;    // padded bucket base (8-aligned)

    hist[threadIdx.x] = 0;
    __syncthreads();
    for (int j = beg + (int)threadIdx.x; j < end; j += 512)
        atomicAdd(&hist[binned[j] & 511u], 1);
    __syncthreads();

    const int mydeg = hist[threadIdx.x];
    const int mypc = (mydeg + 7) & ~7;               // padded count
    pfx[threadIdx.x] = mypc;
    __syncthreads();
    #pragma unroll
    for (int off = 1; off < 512; off <<= 1) {
        int t = (threadIdx.x >= (unsigned)off) ? pfx[threadIdx.x - off] : 0;
        __syncthreads();
        pfx[threadIdx.x] += t;
        __syncthreads();
    }
    const int myexcl = pfx[threadIdx.x] - mypc;

    const int node = node0 + (int)threadIdx.x;
    if (node < n) {
        row_start[node] = pbeg + myexcl;
        degv[node] = mydeg;
    }
    __syncthreads();

    pfx[threadIdx.x] = myexcl;   // per-node padded start (exclusive)
    hist[threadIdx.x] = 0;       // reuse as per-node cursor
    __syncthreads();

    for (int j = beg + (int)threadIdx.x; j < end; j += 512) {
        unsigned p = binned[j];
        int dl = (int)(p & 511u);
        int pos = pbeg + pfx[dl] + atomicAdd(&hist[dl], 1);
        ssrc[pos] = (int)(p >> NB_SHIFT);
    }
    __syncthreads();

    // fill pad slots of own node with dummy src = n (zero row)
    if (node < n) {
        int base = pbeg + myexcl;
        for (int k = mydeg; k < mypc; ++k) ssrc[base + k] = n;
    }
}

// ---------------- weight pre-transpose + zero-row init ----------------
__global__ __launch_bounds__(256) void transpose_w_kernel(
        const float* __restrict__ W0, const float* __restrict__ W1,
        const float* __restrict__ W2, unsigned short* __restrict__ Wt) {
    int i = blockIdx.x * 256 + threadIdx.x;     // 0 .. 3*16384-1
    int w = i >> 14;
    int r = i & 16383;
    int k = r >> 7, c = r & 127;
    const float* W = (w == 0) ? W0 : ((w == 1) ? W1 : W2);
    Wt[(size_t)w * 16384 + c * 128 + k] = bf16_of(W[r]);
}

// zero feature row N in all three state buffers (dummy-edge target): 3 rows x
// 16 uint4 = 48 threads.
__global__ void zero_rows_kernel(unsigned short* __restrict__ Xb,
                                 unsigned short* __restrict__ U0,
                                 unsigned short* __restrict__ U1, int n) {
    int t = threadIdx.x;
    if (t >= 48) return;
    unsigned short* base = (t < 16) ? Xb : ((t < 32) ? U0 : U1);
    uint4v z = {0u, 0u, 0u, 0u};
    *((uint4v*)(base + (size_t)n * 128) + (t & 15)) = z;
}

// ---------------- MFMA GEMM 1: [nrows x 128] fp32 @ W_in -> bf16, no LDS ----
__global__ __launch_bounds__(256) void gemm1_kernel(
        const float* __restrict__ Ap, const unsigned short* __restrict__ Wt,
        const float* __restrict__ bias, unsigned short* __restrict__ outp, int nrows) {
    const int wave = threadIdx.x >> 6;
    const int lane = threadIdx.x & 63;
    const int lhi = lane >> 4;
    const int llo = lane & 15;

    const int rbase = blockIdx.x * 128 + wave * 32;

    f32x4 acc[2][8] = {};

    #pragma unroll
    for (int ks = 0; ks < 4; ++ks) {
        const int k0 = ks * 32 + lhi * 8;
        short8 afrag[2];
        #pragma unroll
        for (int rt = 0; rt < 2; ++rt) {
            int r = rbase + rt * 16 + llo;
            if (r < nrows) {
                const float* ap = Ap + (size_t)r * 128 + k0;
                float4 f0 = *(const float4*)ap;
                float4 f1 = *(const float4*)(ap + 4);
                union { unsigned u[4]; short8 s; } cvt;
                cvt.u[0] = pack_bf2(f0.x, f0.y);
                cvt.u[1] = pack_bf2(f0.z, f0.w);
                cvt.u[2] = pack_bf2(f1.x, f1.y);
                cvt.u[3] = pack_bf2(f1.z, f1.w);
                afrag[rt] = cvt.s;
            } else {
                afrag[rt] = short8{0, 0, 0, 0, 0, 0, 0, 0};
            }
        }
        #pragma unroll
        for (int ct = 0; ct < 8; ++ct) {
            short8 bfrag = *(const short8*)(Wt + (size_t)(ct * 16 + llo) * 128 + k0);
            acc[0][ct] = __builtin_amdgcn_mfma_f32_16x16x32_bf16(afrag[0], bfrag, acc[0][ct], 0, 0, 0);
            acc[1][ct] = __builtin_amdgcn_mfma_f32_16x16x32_bf16(afrag[1], bfrag, acc[1][ct], 0, 0, 0);
        }
    }

    float bv[8];
    #pragma unroll
    for (int ct = 0; ct < 8; ++ct) bv[ct] = bias[ct * 16 + llo];

    #pragma unroll
    for (int rt = 0; rt < 2; ++rt) {
        int rb = rbase + rt * 16 + lhi * 4;
        #pragma unroll
        for (int reg = 0; reg < 4; ++reg) {
            int r = rb + reg;
            if (r >= nrows) continue;
            unsigned short* orow = outp + (size_t)r * 128;
            #pragma unroll
            for (int ct = 0; ct < 8; ++ct) {
                float v = silu_f(acc[rt][ct][reg] + bv[ct]);
                orow[ct * 16 + llo] = bf16_of(v);
            }
        }
    }
}

// ---------------- fused GEMM2+GEMM3: out = silu(U@W1+b1) @ W2 + b2 ----------
// 64-row block tile (wave owns 16 rows) -> 17.4 KB LDS -> 8 blocks/CU.
// x2 never touches HBM.
__global__ __launch_bounds__(256) void gemm23_fused_kernel(
        const unsigned short* __restrict__ U,
        const unsigned short* __restrict__ W1t, const float* __restrict__ b1,
        const unsigned short* __restrict__ W2t, const float* __restrict__ b2,
        float* __restrict__ out, int nrows) {
    constexpr int LDX = 136;
    __shared__ unsigned short sX[64 * LDX];   // 17408 B

    const int wave = threadIdx.x >> 6;
    const int lane = threadIdx.x & 63;
    const int lhi = lane >> 4;
    const int llo = lane & 15;

    const int rbase = blockIdx.x * 64 + wave * 16;
    const int lbase = wave * 16;

    // ---- phase 1: acc = U_tile @ W1, silu -> sX ----
    {
        f32x4 acc[8] = {};
        #pragma unroll
        for (int ks = 0; ks < 4; ++ks) {
            const int k0 = ks * 32 + lhi * 8;
            int r = rbase + llo;
            short8 afrag = (r < nrows)
                ? *(const short8*)(U + (size_t)r * 128 + k0)
                : short8{0, 0, 0, 0, 0, 0, 0, 0};
            #pragma unroll
            for (int ct = 0; ct < 8; ++ct) {
                short8 bfrag = *(const short8*)(W1t + (size_t)(ct * 16 + llo) * 128 + k0);
                acc[ct] = __builtin_amdgcn_mfma_f32_16x16x32_bf16(afrag, bfrag, acc[ct], 0, 0, 0);
            }
        }
        #pragma unroll
        for (int reg = 0; reg < 4; ++reg) {
            unsigned short* srow = sX + (size_t)(lbase + lhi * 4 + reg) * LDX;
            #pragma unroll
            for (int ct = 0; ct < 8; ++ct) {
                float v = silu_f(acc[ct][reg] + b1[ct * 16 + llo]);
                srow[ct * 16 + llo] = bf16_of(v);
            }
        }
    }
    __syncthreads();

    // ---- phase 2: out = sX @ W2 + b2 ----
    f32x4 acc[8] = {};
    #pragma unroll
    for (int ks = 0; ks < 4; ++ks) {
        const int k0 = ks * 32 + lhi * 8;
        short8 afrag = *(const short8*)(sX + (size_t)(lbase + llo) * LDX + k0);
        #pragma unroll
        for (int ct = 0; ct < 8; ++ct) {
            short8 bfrag = *(const short8*)(W2t + (size_t)(ct * 16 + llo) * 128 + k0);
            acc[ct] = __builtin_amdgcn_mfma_f32_16x16x32_bf16(afrag, bfrag, acc[ct], 0, 0, 0);
        }
    }
    #pragma unroll
    for (int reg = 0; reg < 4; ++reg) {
        int r = rbase + lhi * 4 + reg;
        if (r >= nrows) continue;
        float* orow = out + (size_t)r * 128;
        #pragma unroll
        for (int ct = 0; ct < 8; ++ct)
            orow[ct * 16 + llo] = acc[ct][reg] + b2[ct * 16 + llo];
    }
}

// ---------------- Horner diffusion step, row-major bf16, padded CSR ---------

#define ACC8(v)                                          \
    do {                                                 \
        a0 += __uint_as_float((v).x << 16);              \
        a1 += __uint_as_float((v).x & 0xffff0000u);      \
        a2 += __uint_as_float((v).y << 16);              \
        a3 += __uint_as_float((v).y & 0xffff0000u);      \
        a4 += __uint_as_float((v).z << 16);              \
        a5 += __uint_as_float((v).z & 0xffff0000u);      \
        a6 += __uint_as_float((v).w << 16);              \
        a7 += __uint_as_float((v).w & 0xffff0000u);      \
    } while (0)

__global__ __launch_bounds__(256) void horner_bf_kernel(
        const uint4v* __restrict__ u, const uint4v* __restrict__ xb,
        uint4v* __restrict__ u_next,
        const int* __restrict__ row_start, const int* __restrict__ degv,
        const int* __restrict__ ssrc,
        float inv_i, int nrows) {
    const int lt = threadIdx.x & 15;                 // lane within row group
    const int row = blockIdx.x * 16 + (threadIdx.x >> 4);
    if (row >= nrows) return;

    const int beg = row_start[row];
    const int deg = degv[row];
    const int pend = beg + ((deg + 7) & ~7);

    float a0 = 0.f, a1 = 0.f, a2 = 0.f, a3 = 0.f,
          a4 = 0.f, a5 = 0.f, a6 = 0.f, a7 = 0.f;

    for (int j = beg; j < pend; j += 8) {
        int4 sA = *(const int4*)(ssrc + j);
        int4 sB = *(const int4*)(ssrc + j + 4);
        uint4v t0 = u[(size_t)sA.x * 16 + lt];
        uint4v t1 = u[(size_t)sA.y * 16 + lt];
        uint4v t2 = u[(size_t)sA.z * 16 + lt];
        uint4v t3 = u[(size_t)sA.w * 16 + lt];
        uint4v t4 = u[(size_t)sB.x * 16 + lt];
        uint4v t5 = u[(size_t)sB.y * 16 + lt];
        uint4v t6 = u[(size_t)sB.z * 16 + lt];
        uint4v t7 = u[(size_t)sB.w * 16 + lt];
        ACC8(t0); ACC8(t1); ACC8(t2); ACC8(t3);
        ACC8(t4); ACC8(t5); ACC8(t6); ACC8(t7);
    }

    const float scale = inv_i / (float)(deg > 1 ? deg : 1);
    const size_t o = (size_t)row * 16 + lt;
    uint4v xv = xb[o];
    float r0 = fmaf(a0, scale, __uint_as_float(xv.x << 16));
    float r1 = fmaf(a1, scale, __uint_as_float(xv.x & 0xffff0000u));
    float r2 = fmaf(a2, scale, __uint_as_float(xv.y << 16));
    float r3 = fmaf(a3, scale, __uint_as_float(xv.y & 0xffff0000u));
    float r4 = fmaf(a4, scale, __uint_as_float(xv.z << 16));
    float r5 = fmaf(a5, scale, __uint_as_float(xv.z & 0xffff0000u));
    float r6 = fmaf(a6, scale, __uint_as_float(xv.w << 16));
    float r7 = fmaf(a7, scale, __uint_as_float(xv.w & 0xffff0000u));
    uint4v ov;
    ov.x = pack_bf2(r0, r1);
    ov.y = pack_bf2(r2, r3);
    ov.z = pack_bf2(r4, r5);
    ov.w = pack_bf2(r6, r7);
    u_next[o] = ov;
}

// ---------------- launch ----------------

extern "C" void kernel_launch(void* const* d_in, const int* in_sizes, int n_in,
                              void* d_out, int out_size, void* d_ws, size_t ws_size,
                              hipStream_t stream) {
    const float* h      = (const float*)d_in[0];
    const int*   eidx   = (const int*)d_in[1];
    const float* W_in   = (const float*)d_in[2];
    const float* b_in   = (const float*)d_in[3];
    const float* W1     = (const float*)d_in[4];
    const float* b1     = (const float*)d_in[5];
    const float* W2     = (const float*)d_in[6];
    const float* b2     = (const float*)d_in[7];
    float* out = (float*)d_out;

    const int N = in_sizes[0] / D;      // 100000
    const int E = in_sizes[1] / 2;      // 1600000
    const int NB = (N + (1 << NB_SHIFT) - 1) >> NB_SHIFT;   // 196 buckets

    const int* e_src = eidx;
    const int* e_dst = eidx + E;

    const size_t rowsz = (size_t)(N + 1) * 128;   // +1 zero row for dummy edges

    // workspace layout
    unsigned short* Xb = (unsigned short*)d_ws;         // (N+1)*128 shorts
    unsigned short* U0 = Xb + rowsz;                    // (N+1)*128 shorts
    unsigned short* U1 = U0 + rowsz;                    // (N+1)*128 shorts
    unsigned short* Wt = U1 + rowsz;                    // 3*16384 shorts
    unsigned* binned   = (unsigned*)(Wt + 3 * 16384);   // E
    int* ssrc        = (int*)(binned + E);              // E + NB*BPAD + 16
    int* row_start   = ssrc + E + NB * BPAD + 16;       // N
    int* degv        = row_start + N;                   // N
    int* bucket_cnt  = degv + N;                        // 256
    int* bucket_base = bucket_cnt + 256;                // 256
    int* bin_cur     = bucket_base + 256;               // 256

    hipMemsetAsync(bucket_cnt, 0, 256 * sizeof(int), stream);
    zero_rows_kernel<<<1, 64, 0, stream>>>(Xb, U0, U1, N);

    const int eb = (E + 256 * CPT - 1) / (256 * CPT);
    bucket_hist_kernel<<<eb, 256, 0, stream>>>(e_dst, bucket_cnt, E, NB);
    scan_buckets_kernel<<<1, 256, 0, stream>>>(bucket_cnt, bucket_base, bin_cur, NB);
    bin_edges_kernel<<<eb, 256, 0, stream>>>(e_src, e_dst, bin_cur, binned, E, NB);
    bucket_csr_kernel<<<NB, 512, 0, stream>>>(binned, bucket_base, row_start, degv,
                                              ssrc, N, E, NB);

    // weight pre-transpose (bf16 W^T for all three GEMMs)
    transpose_w_kernel<<<192, 256, 0, stream>>>(W_in, W1, W2, Wt);

    const int gb = (N + 127) / 128;
    // Xb = bf16(silu(h @ W_in + b_in))
    gemm1_kernel<<<gb, 256, 0, stream>>>(h, Wt, b_in, Xb, N);

    // Horner: u = x; for i = K..1: u = x + (A u)/i   (bf16 state)
    const int db = (N + 15) / 16;
    const uint4v* Xv = (const uint4v*)Xb;
    uint4v* U0v = (uint4v*)U0;
    uint4v* U1v = (uint4v*)U1;
    horner_bf_kernel<<<db, 256, 0, stream>>>(Xv, Xv, U0v, row_start, degv, ssrc, 1.0f / 6.0f, N);
    horner_bf_kernel<<<db, 256, 0, stream>>>(U0v, Xv, U1v, row_start, degv, ssrc, 1.0f / 5.0f, N);
    horner_bf_kernel<<<db, 256, 0, stream>>>(U1v, Xv, U0v, row_start, degv, ssrc, 1.0f / 4.0f, N);
    horner_bf_kernel<<<db, 256, 0, stream>>>(U0v, Xv, U1v, row_start, degv, ssrc, 1.0f / 3.0f, N);
    horner_bf_kernel<<<db, 256, 0, stream>>>(U1v, Xv, U0v, row_start, degv, ssrc, 1.0f / 2.0f, N);
    horner_bf_kernel<<<db, 256, 0, stream>>>(U0v, Xv, U1v, row_start, degv, ssrc, 1.0f, N);
    // final diffusion result: U1 (bf16)

    // out = silu(U1 @ W1 + b1) @ W2 + b2   (fused, x2 stays in LDS)
    const int gb2 = (N + 63) / 64;
    gemm23_fused_kernel<<<gb2, 256, 0, stream>>>(U1, Wt + 16384, b1,
                                                 Wt + 2 * 16384, b2, out, N);
}

// Round 13
// 530.846 us; speedup vs baseline: 1.0055x; 1.0055x over previous
//
#include <hip/hip_runtime.h>

#define D 128
#define K_ORDER 6
#define NB_SHIFT 9           // bucket = dst >> 9 (512 nodes/bucket)
#define CPT 8                // edges per thread in binning passes
#define BPAD 4096            // per-bucket padded slack (>= 512*7 + 8)

typedef __attribute__((ext_vector_type(8))) short short8;
typedef __attribute__((ext_vector_type(4))) float f32x4;
typedef __attribute__((ext_vector_type(4))) unsigned uint4v;

__device__ __forceinline__ float silu_f(float x) {
    return x / (1.0f + __expf(-x));
}

__device__ __forceinline__ unsigned pack_bf2(float lo, float hi) {
    unsigned ul = __float_as_uint(lo);
    unsigned uh = __float_as_uint(hi);
    ul = (ul + 0x7fffu + ((ul >> 16) & 1u)) >> 16;          // RNE
    uh = (uh + 0x7fffu + ((uh >> 16) & 1u)) & 0xffff0000u;  // RNE, keep high
    return uh | ul;
}

__device__ __forceinline__ unsigned short bf16_of(float f) {
    unsigned u = __float_as_uint(f);
    u = (u + 0x7fffu + ((u >> 16) & 1u)) >> 16;
    return (unsigned short)u;
}

// ---------------- CSR build (no global atomics on per-node arrays) ----------

__global__ __launch_bounds__(256) void bucket_hist_kernel(
        const int* __restrict__ dst, int* __restrict__ bucket_cnt, int e, int nb) {
    __shared__ int hist[256];
    for (int i = threadIdx.x; i < 256; i += 256) hist[i] = 0;
    __syncthreads();
    int i0 = blockIdx.x * (256 * CPT) + threadIdx.x;
    #pragma unroll
    for (int k = 0; k < CPT; ++k) {
        int idx = i0 + k * 256;
        if (idx < e) atomicAdd(&hist[dst[idx] >> NB_SHIFT], 1);
    }
    __syncthreads();
    for (int i = threadIdx.x; i < nb; i += 256) {
        int h = hist[i];
        if (h) atomicAdd(&bucket_cnt[i], h);
    }
}

__global__ __launch_bounds__(256) void scan_buckets_kernel(
        const int* __restrict__ bucket_cnt, int* __restrict__ bucket_base,
        int* __restrict__ bin_cur, int nb) {
    __shared__ int lds[256];
    int v = (threadIdx.x < (unsigned)nb) ? bucket_cnt[threadIdx.x] : 0;
    lds[threadIdx.x] = v;
    __syncthreads();
    #pragma unroll
    for (int off = 1; off < 256; off <<= 1) {
        int t = (threadIdx.x >= (unsigned)off) ? lds[threadIdx.x - off] : 0;
        __syncthreads();
        lds[threadIdx.x] += t;
        __syncthreads();
    }
    if (threadIdx.x < (unsigned)nb) {
        int b = lds[threadIdx.x] - v;
        bucket_base[threadIdx.x] = b;
        bin_cur[threadIdx.x] = b;
    }
}

__global__ __launch_bounds__(256) void bin_edges_kernel(
        const int* __restrict__ src, const int* __restrict__ dst,
        int* __restrict__ bin_cur, unsigned* __restrict__ binned, int e, int nb) {
    __shared__ int hist[256];
    __shared__ int base[256];
    for (int i = threadIdx.x; i < 256; i += 256) hist[i] = 0;
    __syncthreads();

    int e0 = blockIdx.x * (256 * CPT) + threadIdx.x;
    int myb[CPT], myoff[CPT];
    unsigned mypk[CPT];
    #pragma unroll
    for (int k = 0; k < CPT; ++k) {
        int idx = e0 + k * 256;
        bool ok = idx < e;
        int d = ok ? dst[idx] : 0;
        int s = ok ? src[idx] : 0;
        int b = d >> NB_SHIFT;
        int off = ok ? atomicAdd(&hist[b], 1) : 0;
        myb[k] = b; myoff[k] = off;
        mypk[k] = ((unsigned)s << NB_SHIFT) | (unsigned)(d & ((1 << NB_SHIFT) - 1));
    }
    __syncthreads();
    for (int i = threadIdx.x; i < nb; i += 256) {
        int h = hist[i];
        base[i] = h ? atomicAdd(&bin_cur[i], h) : 0;
    }
    __syncthreads();
    #pragma unroll
    for (int k = 0; k < CPT; ++k) {
        int idx = e0 + k * 256;
        if (idx < e)
            binned[(size_t)base[myb[k]] + myoff[k]] = mypk[k];
    }
}

// Per-bucket CSR finalize with 8-padding: each row's edge list is padded to a
// multiple of 8 with dummy src = n (zero feature row). row_start is 8-aligned.
__global__ __launch_bounds__(512) void bucket_csr_kernel(
        const unsigned* __restrict__ binned, const int* __restrict__ bucket_base,
        int* __restrict__ row_start, int* __restrict__ degv,
        int* __restrict__ ssrc, int n, int e, int nb) {
    __shared__ int hist[512];
    __shared__ int pfx[512];
    const int b = blockIdx.x;
    const int node0 = b << NB_SHIFT;
    const int beg = bucket_base[b];
    const int end = (b + 1 < nb) ? bucket_base[b + 1] : e;
    const int pbeg = ((beg + 7) & ~7) + b * BPAD;    // padded bucket base (8-aligned)

    hist[threadIdx.x] = 0;
    __syncthreads();
    for (int j = beg + (int)threadIdx.x; j < end; j += 512)
        atomicAdd(&hist[binned[j] & 511u], 1);
    __syncthreads();

    const int mydeg = hist[threadIdx.x];
    const int mypc = (mydeg + 7) & ~7;               // padded count
    pfx[threadIdx.x] = mypc;
    __syncthreads();
    #pragma unroll
    for (int off = 1; off < 512; off <<= 1) {
        int t = (threadIdx.x >= (unsigned)off) ? pfx[threadIdx.x - off] : 0;
        __syncthreads();
        pfx[threadIdx.x] += t;
        __syncthreads();
    }
    const int myexcl = pfx[threadIdx.x] - mypc;

    const int node = node0 + (int)threadIdx.x;
    if (node < n) {
        row_start[node] = pbeg + myexcl;
        degv[node] = mydeg;
    }
    __syncthreads();

    pfx[threadIdx.x] = myexcl;   // per-node padded start (exclusive)
    hist[threadIdx.x] = 0;       // reuse as per-node cursor
    __syncthreads();

    for (int j = beg + (int)threadIdx.x; j < end; j += 512) {
        unsigned p = binned[j];
        int dl = (int)(p & 511u);
        int pos = pbeg + pfx[dl] + atomicAdd(&hist[dl], 1);
        ssrc[pos] = (int)(p >> NB_SHIFT);
    }
    __syncthreads();

    // fill pad slots of own node with dummy src = n (zero row)
    if (node < n) {
        int base = pbeg + myexcl;
        for (int k = mydeg; k < mypc; ++k) ssrc[base + k] = n;
    }
}

// ---------------- weight pre-transpose + zero-row init ----------------
__global__ __launch_bounds__(256) void transpose_w_kernel(
        const float* __restrict__ W0, const float* __restrict__ W1,
        const float* __restrict__ W2, unsigned short* __restrict__ Wt) {
    int i = blockIdx.x * 256 + threadIdx.x;     // 0 .. 3*16384-1
    int w = i >> 14;
    int r = i & 16383;
    int k = r >> 7, c = r & 127;
    const float* W = (w == 0) ? W0 : ((w == 1) ? W1 : W2);
    Wt[(size_t)w * 16384 + c * 128 + k] = bf16_of(W[r]);
}

// zero feature row N in all three state buffers (dummy-edge target)
__global__ void zero_rows_kernel(unsigned short* __restrict__ Xb,
                                 unsigned short* __restrict__ U0,
                                 unsigned short* __restrict__ U1, int n) {
    int t = threadIdx.x;
    if (t >= 48) return;
    unsigned short* base = (t < 16) ? Xb : ((t < 32) ? U0 : U1);
    uint4v z = {0u, 0u, 0u, 0u};
    *((uint4v*)(base + (size_t)n * 128) + (t & 15)) = z;
}

// ---------------- MFMA GEMM 1: [nrows x 128] fp32 @ W_in -> bf16 ------------
// MLP-restructured: all 16 A loads issued up-front; per K-step the 8 B-frags
// batch-load into bf[8] before any MFMA consumes them.
__global__ __launch_bounds__(256) void gemm1_kernel(
        const float* __restrict__ Ap, const unsigned short* __restrict__ Wt,
        const float* __restrict__ bias, unsigned short* __restrict__ outp, int nrows) {
    const int wave = threadIdx.x >> 6;
    const int lane = threadIdx.x & 63;
    const int lhi = lane >> 4;
    const int llo = lane & 15;

    const int rbase = blockIdx.x * 128 + wave * 32;

    // preload + convert all A fragments (16 independent global loads)
    short8 af[2][4];
    #pragma unroll
    for (int rt = 0; rt < 2; ++rt) {
        int r = rbase + rt * 16 + llo;
        bool ok = r < nrows;
        const float* ap = Ap + (size_t)r * 128 + lhi * 8;
        #pragma unroll
        for (int ks = 0; ks < 4; ++ks) {
            float4 f0 = ok ? *(const float4*)(ap + ks * 32) : make_float4(0.f, 0.f, 0.f, 0.f);
            float4 f1 = ok ? *(const float4*)(ap + ks * 32 + 4) : make_float4(0.f, 0.f, 0.f, 0.f);
            union { unsigned u[4]; short8 s; } cvt;
            cvt.u[0] = pack_bf2(f0.x, f0.y);
            cvt.u[1] = pack_bf2(f0.z, f0.w);
            cvt.u[2] = pack_bf2(f1.x, f1.y);
            cvt.u[3] = pack_bf2(f1.z, f1.w);
            af[rt][ks] = cvt.s;
        }
    }

    f32x4 acc[2][8] = {};
    #pragma unroll
    for (int ks = 0; ks < 4; ++ks) {
        const int k0 = ks * 32 + lhi * 8;
        short8 bf[8];
        #pragma unroll
        for (int ct = 0; ct < 8; ++ct)
            bf[ct] = *(const short8*)(Wt + (size_t)(ct * 16 + llo) * 128 + k0);
        #pragma unroll
        for (int ct = 0; ct < 8; ++ct) {
            acc[0][ct] = __builtin_amdgcn_mfma_f32_16x16x32_bf16(af[0][ks], bf[ct], acc[0][ct], 0, 0, 0);
            acc[1][ct] = __builtin_amdgcn_mfma_f32_16x16x32_bf16(af[1][ks], bf[ct], acc[1][ct], 0, 0, 0);
        }
    }

    float bv[8];
    #pragma unroll
    for (int ct = 0; ct < 8; ++ct) bv[ct] = bias[ct * 16 + llo];

    #pragma unroll
    for (int rt = 0; rt < 2; ++rt) {
        int rb = rbase + rt * 16 + lhi * 4;
        #pragma unroll
        for (int reg = 0; reg < 4; ++reg) {
            int r = rb + reg;
            if (r >= nrows) continue;
            unsigned short* orow = outp + (size_t)r * 128;
            #pragma unroll
            for (int ct = 0; ct < 8; ++ct) {
                float v = silu_f(acc[rt][ct][reg] + bv[ct]);
                orow[ct * 16 + llo] = bf16_of(v);
            }
        }
    }
}

// ---------------- fused GEMM2+GEMM3: out = silu(U@W1+b1) @ W2 + b2 ----------
// 64-row tile (wave owns 16 rows), 17.4 KB LDS. Same batched-load structure:
// A-frags (4 loads) up-front, B-frags per K-step into bf[8] before MFMAs.
__global__ __launch_bounds__(256) void gemm23_fused_kernel(
        const unsigned short* __restrict__ U,
        const unsigned short* __restrict__ W1t, const float* __restrict__ b1,
        const unsigned short* __restrict__ W2t, const float* __restrict__ b2,
        float* __restrict__ out, int nrows) {
    constexpr int LDX = 136;
    __shared__ unsigned short sX[64 * LDX];   // 17408 B

    const int wave = threadIdx.x >> 6;
    const int lane = threadIdx.x & 63;
    const int lhi = lane >> 4;
    const int llo = lane & 15;

    const int rbase = blockIdx.x * 64 + wave * 16;
    const int lbase = wave * 16;

    // ---- phase 1: sX = silu(U_tile @ W1 + b1) ----
    {
        int r = rbase + llo;
        bool ok = r < nrows;
        short8 af[4];
        #pragma unroll
        for (int ks = 0; ks < 4; ++ks)
            af[ks] = ok ? *(const short8*)(U + (size_t)r * 128 + ks * 32 + lhi * 8)
                        : short8{0, 0, 0, 0, 0, 0, 0, 0};

        f32x4 acc[8] = {};
        #pragma unroll
        for (int ks = 0; ks < 4; ++ks) {
            const int k0 = ks * 32 + lhi * 8;
            short8 bf[8];
            #pragma unroll
            for (int ct = 0; ct < 8; ++ct)
                bf[ct] = *(const short8*)(W1t + (size_t)(ct * 16 + llo) * 128 + k0);
            #pragma unroll
            for (int ct = 0; ct < 8; ++ct)
                acc[ct] = __builtin_amdgcn_mfma_f32_16x16x32_bf16(af[ks], bf[ct], acc[ct], 0, 0, 0);
        }
        float bv[8];
        #pragma unroll
        for (int ct = 0; ct < 8; ++ct) bv[ct] = b1[ct * 16 + llo];
        #pragma unroll
        for (int reg = 0; reg < 4; ++reg) {
            unsigned short* srow = sX + (size_t)(lbase + lhi * 4 + reg) * LDX;
            #pragma unroll
            for (int ct = 0; ct < 8; ++ct) {
                float v = silu_f(acc[ct][reg] + bv[ct]);
                srow[ct * 16 + llo] = bf16_of(v);
            }
        }
    }
    __syncthreads();

    // ---- phase 2: out = sX @ W2 + b2 ----
    short8 af[4];
    #pragma unroll
    for (int ks = 0; ks < 4; ++ks)
        af[ks] = *(const short8*)(sX + (size_t)(lbase + llo) * LDX + ks * 32 + lhi * 8);

    f32x4 acc[8] = {};
    #pragma unroll
    for (int ks = 0; ks < 4; ++ks) {
        const int k0 = ks * 32 + lhi * 8;
        short8 bf[8];
        #pragma unroll
        for (int ct = 0; ct < 8; ++ct)
            bf[ct] = *(const short8*)(W2t + (size_t)(ct * 16 + llo) * 128 + k0);
        #pragma unroll
        for (int ct = 0; ct < 8; ++ct)
            acc[ct] = __builtin_amdgcn_mfma_f32_16x16x32_bf16(af[ks], bf[ct], acc[ct], 0, 0, 0);
    }
    float bv[8];
    #pragma unroll
    for (int ct = 0; ct < 8; ++ct) bv[ct] = b2[ct * 16 + llo];
    #pragma unroll
    for (int reg = 0; reg < 4; ++reg) {
        int r = rbase + lhi * 4 + reg;
        if (r >= nrows) continue;
        float* orow = out + (size_t)r * 128;
        #pragma unroll
        for (int ct = 0; ct < 8; ++ct)
            orow[ct * 16 + llo] = acc[ct][reg] + bv[ct];
    }
}

// ---------------- Horner diffusion step, row-major bf16, padded CSR ---------

#define ACC8(v)                                          \
    do {                                                 \
        a0 += __uint_as_float((v).x << 16);              \
        a1 += __uint_as_float((v).x & 0xffff0000u);      \
        a2 += __uint_as_float((v).y << 16);              \
        a3 += __uint_as_float((v).y & 0xffff0000u);      \
        a4 += __uint_as_float((v).z << 16);              \
        a5 += __uint_as_float((v).z & 0xffff0000u);      \
        a6 += __uint_as_float((v).w << 16);              \
        a7 += __uint_as_float((v).w & 0xffff0000u);      \
    } while (0)

__global__ __launch_bounds__(256) void horner_bf_kernel(
        const uint4v* __restrict__ u, const uint4v* __restrict__ xb,
        uint4v* __restrict__ u_next,
        const int* __restrict__ row_start, const int* __restrict__ degv,
        const int* __restrict__ ssrc,
        float inv_i, int nrows) {
    const int lt = threadIdx.x & 15;                 // lane within row group
    const int row = blockIdx.x * 16 + (threadIdx.x >> 4);
    if (row >= nrows) return;

    const int beg = row_start[row];
    const int deg = degv[row];
    const int pend = beg + ((deg + 7) & ~7);

    float a0 = 0.f, a1 = 0.f, a2 = 0.f, a3 = 0.f,
          a4 = 0.f, a5 = 0.f, a6 = 0.f, a7 = 0.f;

    for (int j = beg; j < pend; j += 8) {
        int4 sA = *(const int4*)(ssrc + j);
        int4 sB = *(const int4*)(ssrc + j + 4);
        uint4v t0 = u[(size_t)sA.x * 16 + lt];
        uint4v t1 = u[(size_t)sA.y * 16 + lt];
        uint4v t2 = u[(size_t)sA.z * 16 + lt];
        uint4v t3 = u[(size_t)sA.w * 16 + lt];
        uint4v t4 = u[(size_t)sB.x * 16 + lt];
        uint4v t5 = u[(size_t)sB.y * 16 + lt];
        uint4v t6 = u[(size_t)sB.z * 16 + lt];
        uint4v t7 = u[(size_t)sB.w * 16 + lt];
        ACC8(t0); ACC8(t1); ACC8(t2); ACC8(t3);
        ACC8(t4); ACC8(t5); ACC8(t6); ACC8(t7);
    }

    const float scale = inv_i / (float)(deg > 1 ? deg : 1);
    const size_t o = (size_t)row * 16 + lt;
    uint4v xv = xb[o];
    float r0 = fmaf(a0, scale, __uint_as_float(xv.x << 16));
    float r1 = fmaf(a1, scale, __uint_as_float(xv.x & 0xffff0000u));
    float r2 = fmaf(a2, scale, __uint_as_float(xv.y << 16));
    float r3 = fmaf(a3, scale, __uint_as_float(xv.y & 0xffff0000u));
    float r4 = fmaf(a4, scale, __uint_as_float(xv.z << 16));
    float r5 = fmaf(a5, scale, __uint_as_float(xv.z & 0xffff0000u));
    float r6 = fmaf(a6, scale, __uint_as_float(xv.w << 16));
    float r7 = fmaf(a7, scale, __uint_as_float(xv.w & 0xffff0000u));
    uint4v ov;
    ov.x = pack_bf2(r0, r1);
    ov.y = pack_bf2(r2, r3);
    ov.z = pack_bf2(r4, r5);
    ov.w = pack_bf2(r6, r7);
    u_next[o] = ov;
}

// ---------------- launch ----------------

extern "C" void kernel_launch(void* const* d_in, const int* in_sizes, int n_in,
                              void* d_out, int out_size, void* d_ws, size_t ws_size,
                              hipStream_t stream) {
    const float* h      = (const float*)d_in[0];
    const int*   eidx   = (const int*)d_in[1];
    const float* W_in   = (const float*)d_in[2];
    const float* b_in   = (const float*)d_in[3];
    const float* W1     = (const float*)d_in[4];
    const float* b1     = (const float*)d_in[5];
    const float* W2     = (const float*)d_in[6];
    const float* b2     = (const float*)d_in[7];
    float* out = (float*)d_out;

    const int N = in_sizes[0] / D;      // 100000
    const int E = in_sizes[1] / 2;      // 1600000
    const int NB = (N + (1 << NB_SHIFT) - 1) >> NB_SHIFT;   // 196 buckets

    const int* e_src = eidx;
    const int* e_dst = eidx + E;

    const size_t rowsz = (size_t)(N + 1) * 128;   // +1 zero row for dummy edges

    // workspace layout
    unsigned short* Xb = (unsigned short*)d_ws;         // (N+1)*128 shorts
    unsigned short* U0 = Xb + rowsz;                    // (N+1)*128 shorts
    unsigned short* U1 = U0 + rowsz;                    // (N+1)*128 shorts
    unsigned short* Wt = U1 + rowsz;                    // 3*16384 shorts
    unsigned* binned   = (unsigned*)(Wt + 3 * 16384);   // E
    int* ssrc        = (int*)(binned + E);              // E + NB*BPAD + 16
    int* row_start   = ssrc + E + NB * BPAD + 16;       // N
    int* degv        = row_start + N;                   // N
    int* bucket_cnt  = degv + N;                        // 256
    int* bucket_base = bucket_cnt + 256;                // 256
    int* bin_cur     = bucket_base + 256;               // 256

    hipMemsetAsync(bucket_cnt, 0, 256 * sizeof(int), stream);
    zero_rows_kernel<<<1, 64, 0, stream>>>(Xb, U0, U1, N);

    const int eb = (E + 256 * CPT - 1) / (256 * CPT);
    bucket_hist_kernel<<<eb, 256, 0, stream>>>(e_dst, bucket_cnt, E, NB);
    scan_buckets_kernel<<<1, 256, 0, stream>>>(bucket_cnt, bucket_base, bin_cur, NB);
    bin_edges_kernel<<<eb, 256, 0, stream>>>(e_src, e_dst, bin_cur, binned, E, NB);
    bucket_csr_kernel<<<NB, 512, 0, stream>>>(binned, bucket_base, row_start, degv,
                                              ssrc, N, E, NB);

    // weight pre-transpose (bf16 W^T for all three GEMMs)
    transpose_w_kernel<<<192, 256, 0, stream>>>(W_in, W1, W2, Wt);

    const int gb = (N + 127) / 128;
    // Xb = bf16(silu(h @ W_in + b_in))
    gemm1_kernel<<<gb, 256, 0, stream>>>(h, Wt, b_in, Xb, N);

    // Horner: u = x; for i = K..1: u = x + (A u)/i   (bf16 state)
    const int db = (N + 15) / 16;
    const uint4v* Xv = (const uint4v*)Xb;
    uint4v* U0v = (uint4v*)U0;
    uint4v* U1v = (uint4v*)U1;
    horner_bf_kernel<<<db, 256, 0, stream>>>(Xv, Xv, U0v, row_start, degv, ssrc, 1.0f / 6.0f, N);
    horner_bf_kernel<<<db, 256, 0, stream>>>(U0v, Xv, U1v, row_start, degv, ssrc, 1.0f / 5.0f, N);
    horner_bf_kernel<<<db, 256, 0, stream>>>(U1v, Xv, U0v, row_start, degv, ssrc, 1.0f / 4.0f, N);
    horner_bf_kernel<<<db, 256, 0, stream>>>(U0v, Xv, U1v, row_start, degv, ssrc, 1.0f / 3.0f, N);
    horner_bf_kernel<<<db, 256, 0, stream>>>(U1v, Xv, U0v, row_start, degv, ssrc, 1.0f / 2.0f, N);
    horner_bf_kernel<<<db, 256, 0, stream>>>(U0v, Xv, U1v, row_start, degv, ssrc, 1.0f, N);
    // final diffusion result: U1 (bf16)

    // out = silu(U1 @ W1 + b1) @ W2 + b2   (fused, x2 stays in LDS)
    const int gb2 = (N + 63) / 64;
    gemm23_fused_kernel<<<gb2, 256, 0, stream>>>(U1, Wt + 16384, b1,
                                                 Wt + 2 * 16384, b2, out, N);
}

// Round 14
// 486.211 us; speedup vs baseline: 1.0978x; 1.0918x over previous
//
#include <hip/hip_runtime.h>

#define D 128
#define K_ORDER 6
#define NB_SHIFT 9           // bucket = dst >> 9 (512 nodes/bucket)
#define CPT 8                // edges per thread in binning passes
#define BPAD 4096            // per-bucket padded slack (>= 512*7 + 8)

typedef __attribute__((ext_vector_type(8))) short short8;
typedef __attribute__((ext_vector_type(4))) float f32x4;
typedef __attribute__((ext_vector_type(4))) unsigned uint4v;

__device__ __forceinline__ float silu_f(float x) {
    return x / (1.0f + __expf(-x));
}

__device__ __forceinline__ unsigned pack_bf2(float lo, float hi) {
    unsigned ul = __float_as_uint(lo);
    unsigned uh = __float_as_uint(hi);
    ul = (ul + 0x7fffu + ((ul >> 16) & 1u)) >> 16;          // RNE
    uh = (uh + 0x7fffu + ((uh >> 16) & 1u)) & 0xffff0000u;  // RNE, keep high
    return uh | ul;
}

__device__ __forceinline__ unsigned short bf16_of(float f) {
    unsigned u = __float_as_uint(f);
    u = (u + 0x7fffu + ((u >> 16) & 1u)) >> 16;
    return (unsigned short)u;
}

// ---------------- CSR build (no global atomics on per-node arrays) ----------

__global__ __launch_bounds__(256) void bucket_hist_kernel(
        const int* __restrict__ dst, int* __restrict__ bucket_cnt, int e, int nb) {
    __shared__ int hist[256];
    for (int i = threadIdx.x; i < 256; i += 256) hist[i] = 0;
    __syncthreads();
    int i0 = blockIdx.x * (256 * CPT) + threadIdx.x;
    #pragma unroll
    for (int k = 0; k < CPT; ++k) {
        int idx = i0 + k * 256;
        if (idx < e) atomicAdd(&hist[dst[idx] >> NB_SHIFT], 1);
    }
    __syncthreads();
    for (int i = threadIdx.x; i < nb; i += 256) {
        int h = hist[i];
        if (h) atomicAdd(&bucket_cnt[i], h);
    }
}

__global__ __launch_bounds__(256) void scan_buckets_kernel(
        const int* __restrict__ bucket_cnt, int* __restrict__ bucket_base,
        int* __restrict__ bin_cur, int nb) {
    __shared__ int lds[256];
    int v = (threadIdx.x < (unsigned)nb) ? bucket_cnt[threadIdx.x] : 0;
    lds[threadIdx.x] = v;
    __syncthreads();
    #pragma unroll
    for (int off = 1; off < 256; off <<= 1) {
        int t = (threadIdx.x >= (unsigned)off) ? lds[threadIdx.x - off] : 0;
        __syncthreads();
        lds[threadIdx.x] += t;
        __syncthreads();
    }
    if (threadIdx.x < (unsigned)nb) {
        int b = lds[threadIdx.x] - v;
        bucket_base[threadIdx.x] = b;
        bin_cur[threadIdx.x] = b;
    }
}

__global__ __launch_bounds__(256) void bin_edges_kernel(
        const int* __restrict__ src, const int* __restrict__ dst,
        int* __restrict__ bin_cur, unsigned* __restrict__ binned, int e, int nb) {
    __shared__ int hist[256];
    __shared__ int base[256];
    for (int i = threadIdx.x; i < 256; i += 256) hist[i] = 0;
    __syncthreads();

    int e0 = blockIdx.x * (256 * CPT) + threadIdx.x;
    int myb[CPT], myoff[CPT];
    unsigned mypk[CPT];
    #pragma unroll
    for (int k = 0; k < CPT; ++k) {
        int idx = e0 + k * 256;
        bool ok = idx < e;
        int d = ok ? dst[idx] : 0;
        int s = ok ? src[idx] : 0;
        int b = d >> NB_SHIFT;
        int off = ok ? atomicAdd(&hist[b], 1) : 0;
        myb[k] = b; myoff[k] = off;
        mypk[k] = ((unsigned)s << NB_SHIFT) | (unsigned)(d & ((1 << NB_SHIFT) - 1));
    }
    __syncthreads();
    for (int i = threadIdx.x; i < nb; i += 256) {
        int h = hist[i];
        base[i] = h ? atomicAdd(&bin_cur[i], h) : 0;
    }
    __syncthreads();
    #pragma unroll
    for (int k = 0; k < CPT; ++k) {
        int idx = e0 + k * 256;
        if (idx < e)
            binned[(size_t)base[myb[k]] + myoff[k]] = mypk[k];
    }
}

// Per-bucket CSR finalize with 8-padding: each row's edge list is padded to a
// multiple of 8 with dummy src = n (zero feature row). row_start is 8-aligned.
__global__ __launch_bounds__(512) void bucket_csr_kernel(
        const unsigned* __restrict__ binned, const int* __restrict__ bucket_base,
        int* __restrict__ row_start, int* __restrict__ degv,
        int* __restrict__ ssrc, int n, int e, int nb) {
    __shared__ int hist[512];
    __shared__ int pfx[512];
    const int b = blockIdx.x;
    const int node0 = b << NB_SHIFT;
    const int beg = bucket_base[b];
    const int end = (b + 1 < nb) ? bucket_base[b + 1] : e;
    const int pbeg = ((beg + 7) & ~7) + b * BPAD;    // padded bucket base (8-aligned)

    hist[threadIdx.x] = 0;
    __syncthreads();
    for (int j = beg + (int)threadIdx.x; j < end; j += 512)
        atomicAdd(&hist[binned[j] & 511u], 1);
    __syncthreads();

    const int mydeg = hist[threadIdx.x];
    const int mypc = (mydeg + 7) & ~7;               // padded count
    pfx[threadIdx.x] = mypc;
    __syncthreads();
    #pragma unroll
    for (int off = 1; off < 512; off <<= 1) {
        int t = (threadIdx.x >= (unsigned)off) ? pfx[threadIdx.x - off] : 0;
        __syncthreads();
        pfx[threadIdx.x] += t;
        __syncthreads();
    }
    const int myexcl = pfx[threadIdx.x] - mypc;

    const int node = node0 + (int)threadIdx.x;
    if (node < n) {
        row_start[node] = pbeg + myexcl;
        degv[node] = mydeg;
    }
    __syncthreads();

    pfx[threadIdx.x] = myexcl;   // per-node padded start (exclusive)
    hist[threadIdx.x] = 0;       // reuse as per-node cursor
    __syncthreads();

    for (int j = beg + (int)threadIdx.x; j < end; j += 512) {
        unsigned p = binned[j];
        int dl = (int)(p & 511u);
        int pos = pbeg + pfx[dl] + atomicAdd(&hist[dl], 1);
        ssrc[pos] = (int)(p >> NB_SHIFT);
    }
    __syncthreads();

    // fill pad slots of own node with dummy src = n (zero row)
    if (node < n) {
        int base = pbeg + myexcl;
        for (int k = mydeg; k < mypc; ++k) ssrc[base + k] = n;
    }
}

// ---------------- weight pre-transpose + zero-row init ----------------
__global__ __launch_bounds__(256) void transpose_w_kernel(
        const float* __restrict__ W0, const float* __restrict__ W1,
        const float* __restrict__ W2, unsigned short* __restrict__ Wt) {
    int i = blockIdx.x * 256 + threadIdx.x;     // 0 .. 3*16384-1
    int w = i >> 14;
    int r = i & 16383;
    int k = r >> 7, c = r & 127;
    const float* W = (w == 0) ? W0 : ((w == 1) ? W1 : W2);
    Wt[(size_t)w * 16384 + c * 128 + k] = bf16_of(W[r]);
}

// zero feature row N in all three state buffers (dummy-edge target)
__global__ void zero_rows_kernel(unsigned short* __restrict__ Xb,
                                 unsigned short* __restrict__ U0,
                                 unsigned short* __restrict__ U1, int n) {
    int t = threadIdx.x;
    if (t >= 48) return;
    unsigned short* base = (t < 16) ? Xb : ((t < 32) ? U0 : U1);
    uint4v z = {0u, 0u, 0u, 0u};
    *((uint4v*)(base + (size_t)n * 128) + (t & 15)) = z;
}

// stage a 128x128 bf16 W^T (row-major, row = 128 shorts) into LDS with LDW=136
__device__ __forceinline__ void stage_w(unsigned short* __restrict__ sW,
                                        const unsigned short* __restrict__ Wt) {
    #pragma unroll
    for (int i = threadIdx.x; i < 128 * 16; i += 256) {
        int c = i >> 4, q = i & 15;
        *(uint4v*)(sW + c * 136 + q * 8) = *(const uint4v*)(Wt + c * 128 + q * 8);
    }
}

// ---------------- MFMA GEMM 1: [nrows x 128] fp32 @ W_in -> bf16 ------------
// W staged in LDS (straight copy of pre-transposed bf16), B-frags ds_read_b128.
__global__ __launch_bounds__(256) void gemm1_kernel(
        const float* __restrict__ Ap, const unsigned short* __restrict__ Wt,
        const float* __restrict__ bias, unsigned short* __restrict__ outp, int nrows) {
    constexpr int LDW = 136;
    __shared__ unsigned short sW[128 * LDW];   // 34816 B

    stage_w(sW, Wt);
    __syncthreads();

    const int wave = threadIdx.x >> 6;
    const int lane = threadIdx.x & 63;
    const int lhi = lane >> 4;
    const int llo = lane & 15;

    const int rbase = blockIdx.x * 128 + wave * 32;

    // preload + convert all A fragments (16 independent global loads)
    short8 af[2][4];
    #pragma unroll
    for (int rt = 0; rt < 2; ++rt) {
        int r = rbase + rt * 16 + llo;
        bool ok = r < nrows;
        const float* ap = Ap + (size_t)r * 128 + lhi * 8;
        #pragma unroll
        for (int ks = 0; ks < 4; ++ks) {
            float4 f0 = ok ? *(const float4*)(ap + ks * 32) : make_float4(0.f, 0.f, 0.f, 0.f);
            float4 f1 = ok ? *(const float4*)(ap + ks * 32 + 4) : make_float4(0.f, 0.f, 0.f, 0.f);
            union { unsigned u[4]; short8 s; } cvt;
            cvt.u[0] = pack_bf2(f0.x, f0.y);
            cvt.u[1] = pack_bf2(f0.z, f0.w);
            cvt.u[2] = pack_bf2(f1.x, f1.y);
            cvt.u[3] = pack_bf2(f1.z, f1.w);
            af[rt][ks] = cvt.s;
        }
    }

    f32x4 acc[2][8] = {};
    #pragma unroll
    for (int ks = 0; ks < 4; ++ks) {
        const int k0 = ks * 32 + lhi * 8;
        #pragma unroll
        for (int ct = 0; ct < 8; ++ct) {
            short8 bf = *(const short8*)(sW + (size_t)(ct * 16 + llo) * LDW + k0);
            acc[0][ct] = __builtin_amdgcn_mfma_f32_16x16x32_bf16(af[0][ks], bf, acc[0][ct], 0, 0, 0);
            acc[1][ct] = __builtin_amdgcn_mfma_f32_16x16x32_bf16(af[1][ks], bf, acc[1][ct], 0, 0, 0);
        }
    }

    float bv[8];
    #pragma unroll
    for (int ct = 0; ct < 8; ++ct) bv[ct] = bias[ct * 16 + llo];

    #pragma unroll
    for (int rt = 0; rt < 2; ++rt) {
        int rb = rbase + rt * 16 + lhi * 4;
        #pragma unroll
        for (int reg = 0; reg < 4; ++reg) {
            int r = rb + reg;
            if (r >= nrows) continue;
            unsigned short* orow = outp + (size_t)r * 128;
            #pragma unroll
            for (int ct = 0; ct < 8; ++ct) {
                float v = silu_f(acc[rt][ct][reg] + bv[ct]);
                orow[ct * 16 + llo] = bf16_of(v);
            }
        }
    }
}

// ---------------- fused GEMM2+GEMM3: out = silu(U@W1+b1) @ W2 + b2 ----------
// 64-row tile. sW (34.8 KB) staged with W1t for phase 1, re-staged with W2t
// for phase 2; sX (17.4 KB) holds the silu tile. 52.2 KB LDS -> 3 blocks/CU.
// x2 and both W reads never touch HBM/L2 in the inner loops.
__global__ __launch_bounds__(256) void gemm23_fused_kernel(
        const unsigned short* __restrict__ U,
        const unsigned short* __restrict__ W1t, const float* __restrict__ b1,
        const unsigned short* __restrict__ W2t, const float* __restrict__ b2,
        float* __restrict__ out, int nrows) {
    constexpr int LDW = 136;
    constexpr int LDX = 136;
    __shared__ unsigned short sW[128 * LDW];   // 34816 B
    __shared__ unsigned short sX[64 * LDX];    // 17408 B

    const int wave = threadIdx.x >> 6;
    const int lane = threadIdx.x & 63;
    const int lhi = lane >> 4;
    const int llo = lane & 15;

    const int rbase = blockIdx.x * 64 + wave * 16;
    const int lbase = wave * 16;

    stage_w(sW, W1t);

    // A-frags for phase 1 (4 independent global loads, issued before sync)
    int r = rbase + llo;
    bool ok = r < nrows;
    short8 af[4];
    #pragma unroll
    for (int ks = 0; ks < 4; ++ks)
        af[ks] = ok ? *(const short8*)(U + (size_t)r * 128 + ks * 32 + lhi * 8)
                    : short8{0, 0, 0, 0, 0, 0, 0, 0};
    __syncthreads();

    // ---- phase 1: sX = silu(U_tile @ W1 + b1) ----
    {
        f32x4 acc[8] = {};
        #pragma unroll
        for (int ks = 0; ks < 4; ++ks) {
            const int k0 = ks * 32 + lhi * 8;
            #pragma unroll
            for (int ct = 0; ct < 8; ++ct) {
                short8 bf = *(const short8*)(sW + (size_t)(ct * 16 + llo) * LDW + k0);
                acc[ct] = __builtin_amdgcn_mfma_f32_16x16x32_bf16(af[ks], bf, acc[ct], 0, 0, 0);
            }
        }
        float bv[8];
        #pragma unroll
        for (int ct = 0; ct < 8; ++ct) bv[ct] = b1[ct * 16 + llo];
        #pragma unroll
        for (int reg = 0; reg < 4; ++reg) {
            unsigned short* srow = sX + (size_t)(lbase + lhi * 4 + reg) * LDX;
            #pragma unroll
            for (int ct = 0; ct < 8; ++ct) {
                float v = silu_f(acc[ct][reg] + bv[ct]);
                srow[ct * 16 + llo] = bf16_of(v);
            }
        }
    }
    __syncthreads();          // all sW reads + sX writes complete

    stage_w(sW, W2t);         // overwrite with W2t
    __syncthreads();

    // ---- phase 2: out = sX @ W2 + b2 ----
    #pragma unroll
    for (int ks = 0; ks < 4; ++ks)
        af[ks] = *(const short8*)(sX + (size_t)(lbase + llo) * LDX + ks * 32 + lhi * 8);

    f32x4 acc[8] = {};
    #pragma unroll
    for (int ks = 0; ks < 4; ++ks) {
        const int k0 = ks * 32 + lhi * 8;
        #pragma unroll
        for (int ct = 0; ct < 8; ++ct) {
            short8 bf = *(const short8*)(sW + (size_t)(ct * 16 + llo) * LDW + k0);
            acc[ct] = __builtin_amdgcn_mfma_f32_16x16x32_bf16(af[ks], bf, acc[ct], 0, 0, 0);
        }
    }
    float bv[8];
    #pragma unroll
    for (int ct = 0; ct < 8; ++ct) bv[ct] = b2[ct * 16 + llo];
    #pragma unroll
    for (int reg = 0; reg < 4; ++reg) {
        int rr = rbase + lhi * 4 + reg;
        if (rr >= nrows) continue;
        float* orow = out + (size_t)rr * 128;
        #pragma unroll
        for (int ct = 0; ct < 8; ++ct)
            orow[ct * 16 + llo] = acc[ct][reg] + bv[ct];
    }
}

// ---------------- Horner diffusion step, row-major bf16, padded CSR ---------

#define ACC8(v)                                          \
    do {                                                 \
        a0 += __uint_as_float((v).x << 16);              \
        a1 += __uint_as_float((v).x & 0xffff0000u);      \
        a2 += __uint_as_float((v).y << 16);              \
        a3 += __uint_as_float((v).y & 0xffff0000u);      \
        a4 += __uint_as_float((v).z << 16);              \
        a5 += __uint_as_float((v).z & 0xffff0000u);      \
        a6 += __uint_as_float((v).w << 16);              \
        a7 += __uint_as_float((v).w & 0xffff0000u);      \
    } while (0)

__global__ __launch_bounds__(256) void horner_bf_kernel(
        const uint4v* __restrict__ u, const uint4v* __restrict__ xb,
        uint4v* __restrict__ u_next,
        const int* __restrict__ row_start, const int* __restrict__ degv,
        const int* __restrict__ ssrc,
        float inv_i, int nrows) {
    const int lt = threadIdx.x & 15;                 // lane within row group
    const int row = blockIdx.x * 16 + (threadIdx.x >> 4);
    if (row >= nrows) return;

    const int beg = row_start[row];
    const int deg = degv[row];
    const int pend = beg + ((deg + 7) & ~7);

    float a0 = 0.f, a1 = 0.f, a2 = 0.f, a3 = 0.f,
          a4 = 0.f, a5 = 0.f, a6 = 0.f, a7 = 0.f;

    for (int j = beg; j < pend; j += 8) {
        int4 sA = *(const int4*)(ssrc + j);
        int4 sB = *(const int4*)(ssrc + j + 4);
        uint4v t0 = u[(size_t)sA.x * 16 + lt];
        uint4v t1 = u[(size_t)sA.y * 16 + lt];
        uint4v t2 = u[(size_t)sA.z * 16 + lt];
        uint4v t3 = u[(size_t)sA.w * 16 + lt];
        uint4v t4 = u[(size_t)sB.x * 16 + lt];
        uint4v t5 = u[(size_t)sB.y * 16 + lt];
        uint4v t6 = u[(size_t)sB.z * 16 + lt];
        uint4v t7 = u[(size_t)sB.w * 16 + lt];
        ACC8(t0); ACC8(t1); ACC8(t2); ACC8(t3);
        ACC8(t4); ACC8(t5); ACC8(t6); ACC8(t7);
    }

    const float scale = inv_i / (float)(deg > 1 ? deg : 1);
    const size_t o = (size_t)row * 16 + lt;
    uint4v xv = xb[o];
    float r0 = fmaf(a0, scale, __uint_as_float(xv.x << 16));
    float r1 = fmaf(a1, scale, __uint_as_float(xv.x & 0xffff0000u));
    float r2 = fmaf(a2, scale, __uint_as_float(xv.y << 16));
    float r3 = fmaf(a3, scale, __uint_as_float(xv.y & 0xffff0000u));
    float r4 = fmaf(a4, scale, __uint_as_float(xv.z << 16));
    float r5 = fmaf(a5, scale, __uint_as_float(xv.z & 0xffff0000u));
    float r6 = fmaf(a6, scale, __uint_as_float(xv.w << 16));
    float r7 = fmaf(a7, scale, __uint_as_float(xv.w & 0xffff0000u));
    uint4v ov;
    ov.x = pack_bf2(r0, r1);
    ov.y = pack_bf2(r2, r3);
    ov.z = pack_bf2(r4, r5);
    ov.w = pack_bf2(r6, r7);
    u_next[o] = ov;
}

// ---------------- launch ----------------

extern "C" void kernel_launch(void* const* d_in, const int* in_sizes, int n_in,
                              void* d_out, int out_size, void* d_ws, size_t ws_size,
                              hipStream_t stream) {
    const float* h      = (const float*)d_in[0];
    const int*   eidx   = (const int*)d_in[1];
    const float* W_in   = (const float*)d_in[2];
    const float* b_in   = (const float*)d_in[3];
    const float* W1     = (const float*)d_in[4];
    const float* b1     = (const float*)d_in[5];
    const float* W2     = (const float*)d_in[6];
    const float* b2     = (const float*)d_in[7];
    float* out = (float*)d_out;

    const int N = in_sizes[0] / D;      // 100000
    const int E = in_sizes[1] / 2;      // 1600000
    const int NB = (N + (1 << NB_SHIFT) - 1) >> NB_SHIFT;   // 196 buckets

    const int* e_src = eidx;
    const int* e_dst = eidx + E;

    const size_t rowsz = (size_t)(N + 1) * 128;   // +1 zero row for dummy edges

    // workspace layout
    unsigned short* Xb = (unsigned short*)d_ws;         // (N+1)*128 shorts
    unsigned short* U0 = Xb + rowsz;                    // (N+1)*128 shorts
    unsigned short* U1 = U0 + rowsz;                    // (N+1)*128 shorts
    unsigned short* Wt = U1 + rowsz;                    // 3*16384 shorts
    unsigned* binned   = (unsigned*)(Wt + 3 * 16384);   // E
    int* ssrc        = (int*)(binned + E);              // E + NB*BPAD + 16
    int* row_start   = ssrc + E + NB * BPAD + 16;       // N
    int* degv        = row_start + N;                   // N
    int* bucket_cnt  = degv + N;                        // 256
    int* bucket_base = bucket_cnt + 256;                // 256
    int* bin_cur     = bucket_base + 256;               // 256

    hipMemsetAsync(bucket_cnt, 0, 256 * sizeof(int), stream);
    zero_rows_kernel<<<1, 64, 0, stream>>>(Xb, U0, U1, N);

    const int eb = (E + 256 * CPT - 1) / (256 * CPT);
    bucket_hist_kernel<<<eb, 256, 0, stream>>>(e_dst, bucket_cnt, E, NB);
    scan_buckets_kernel<<<1, 256, 0, stream>>>(bucket_cnt, bucket_base, bin_cur, NB);
    bin_edges_kernel<<<eb, 256, 0, stream>>>(e_src, e_dst, bin_cur, binned, E, NB);
    bucket_csr_kernel<<<NB, 512, 0, stream>>>(binned, bucket_base, row_start, degv,
                                              ssrc, N, E, NB);

    // weight pre-transpose (bf16 W^T for all three GEMMs)
    transpose_w_kernel<<<192, 256, 0, stream>>>(W_in, W1, W2, Wt);

    const int gb = (N + 127) / 128;
    // Xb = bf16(silu(h @ W_in + b_in))
    gemm1_kernel<<<gb, 256, 0, stream>>>(h, Wt, b_in, Xb, N);

    // Horner: u = x; for i = K..1: u = x + (A u)/i   (bf16 state)
    const int db = (N + 15) / 16;
    const uint4v* Xv = (const uint4v*)Xb;
    uint4v* U0v = (uint4v*)U0;
    uint4v* U1v = (uint4v*)U1;
    horner_bf_kernel<<<db, 256, 0, stream>>>(Xv, Xv, U0v, row_start, degv, ssrc, 1.0f / 6.0f, N);
    horner_bf_kernel<<<db, 256, 0, stream>>>(U0v, Xv, U1v, row_start, degv, ssrc, 1.0f / 5.0f, N);
    horner_bf_kernel<<<db, 256, 0, stream>>>(U1v, Xv, U0v, row_start, degv, ssrc, 1.0f / 4.0f, N);
    horner_bf_kernel<<<db, 256, 0, stream>>>(U0v, Xv, U1v, row_start, degv, ssrc, 1.0f / 3.0f, N);
    horner_bf_kernel<<<db, 256, 0, stream>>>(U1v, Xv, U0v, row_start, degv, ssrc, 1.0f / 2.0f, N);
    horner_bf_kernel<<<db, 256, 0, stream>>>(U0v, Xv, U1v, row_start, degv, ssrc, 1.0f, N);
    // final diffusion result: U1 (bf16)

    // out = silu(U1 @ W1 + b1) @ W2 + b2   (fused, x2 + W stay in LDS)
    const int gb2 = (N + 63) / 64;
    gemm23_fused_kernel<<<gb2, 256, 0, stream>>>(U1, Wt + 16384, b1,
                                                 Wt + 2 * 16384, b2, out, N);
}

// Round 15
// 467.730 us; speedup vs baseline: 1.1412x; 1.0395x over previous
//
#include <hip/hip_runtime.h>

#define D 128
#define K_ORDER 6
#define NB_SHIFT 9           // bucket = dst >> 9 (512 nodes/bucket)
#define CPT 8                // edges per thread in binning passes
#define BCAP 12288           // fixed bucket capacity (mean 8192 + 45 sigma)
#define BPAD 4096            // per-bucket padding slack (>= 512*7 + 8)
#define BCAPP (BCAP + BPAD)  // padded ssrc region per bucket

typedef __attribute__((ext_vector_type(8))) short short8;
typedef __attribute__((ext_vector_type(4))) float f32x4;
typedef __attribute__((ext_vector_type(4))) unsigned uint4v;

__device__ __forceinline__ float silu_f(float x) {
    return x / (1.0f + __expf(-x));
}

__device__ __forceinline__ unsigned pack_bf2(float lo, float hi) {
    unsigned ul = __float_as_uint(lo);
    unsigned uh = __float_as_uint(hi);
    ul = (ul + 0x7fffu + ((ul >> 16) & 1u)) >> 16;          // RNE
    uh = (uh + 0x7fffu + ((uh >> 16) & 1u)) & 0xffff0000u;  // RNE, keep high
    return uh | ul;
}

__device__ __forceinline__ unsigned short bf16_of(float f) {
    unsigned u = __float_as_uint(f);
    u = (u + 0x7fffu + ((u >> 16) & 1u)) >> 16;
    return (unsigned short)u;
}

// ---------------- CSR build (fixed-capacity buckets, no hist/scan passes) ---

__global__ void init_cur_kernel(int* __restrict__ bin_cur, int nb) {
    int b = threadIdx.x;
    if (b < nb) bin_cur[b] = b * BCAP;
}

__global__ __launch_bounds__(256) void bin_edges_kernel(
        const int* __restrict__ src, const int* __restrict__ dst,
        int* __restrict__ bin_cur, unsigned* __restrict__ binned, int e, int nb) {
    __shared__ int hist[256];
    __shared__ int base[256];
    for (int i = threadIdx.x; i < 256; i += 256) hist[i] = 0;
    __syncthreads();

    int e0 = blockIdx.x * (256 * CPT) + threadIdx.x;
    int myb[CPT], myoff[CPT];
    unsigned mypk[CPT];
    #pragma unroll
    for (int k = 0; k < CPT; ++k) {
        int idx = e0 + k * 256;
        bool ok = idx < e;
        int d = ok ? dst[idx] : 0;
        int s = ok ? src[idx] : 0;
        int b = d >> NB_SHIFT;
        int off = ok ? atomicAdd(&hist[b], 1) : 0;
        myb[k] = b; myoff[k] = off;
        mypk[k] = ((unsigned)s << NB_SHIFT) | (unsigned)(d & ((1 << NB_SHIFT) - 1));
    }
    __syncthreads();
    for (int i = threadIdx.x; i < nb; i += 256) {
        int h = hist[i];
        base[i] = h ? atomicAdd(&bin_cur[i], h) : 0;
    }
    __syncthreads();
    #pragma unroll
    for (int k = 0; k < CPT; ++k) {
        int idx = e0 + k * 256;
        if (idx < e)
            binned[(size_t)base[myb[k]] + myoff[k]] = mypk[k];
    }
}

// Per-bucket CSR finalize with 8-padding: each row's edge list is padded to a
// multiple of 8 with dummy src = n (zero feature row). row_start is 8-aligned.
// Bucket b's binned region = [b*BCAP, bucket_end[b]); ssrc region base b*BCAPP.
__global__ __launch_bounds__(512) void bucket_csr_kernel(
        const unsigned* __restrict__ binned, const int* __restrict__ bucket_end,
        int* __restrict__ row_start, int* __restrict__ degv,
        int* __restrict__ ssrc, int n, int e, int nb) {
    __shared__ int hist[512];
    __shared__ int pfx[512];
    const int b = blockIdx.x;
    const int node0 = b << NB_SHIFT;
    const int beg = b * BCAP;
    const int end = bucket_end[b];
    const int pbeg = b * BCAPP;    // padded ssrc base (8-aligned)

    hist[threadIdx.x] = 0;
    __syncthreads();
    for (int j = beg + (int)threadIdx.x; j < end; j += 512)
        atomicAdd(&hist[binned[j] & 511u], 1);
    __syncthreads();

    const int mydeg = hist[threadIdx.x];
    const int mypc = (mydeg + 7) & ~7;               // padded count
    pfx[threadIdx.x] = mypc;
    __syncthreads();
    #pragma unroll
    for (int off = 1; off < 512; off <<= 1) {
        int t = (threadIdx.x >= (unsigned)off) ? pfx[threadIdx.x - off] : 0;
        __syncthreads();
        pfx[threadIdx.x] += t;
        __syncthreads();
    }
    const int myexcl = pfx[threadIdx.x] - mypc;

    const int node = node0 + (int)threadIdx.x;
    if (node < n) {
        row_start[node] = pbeg + myexcl;
        degv[node] = mydeg;
    }
    __syncthreads();

    pfx[threadIdx.x] = myexcl;   // per-node padded start (exclusive)
    hist[threadIdx.x] = 0;       // reuse as per-node cursor
    __syncthreads();

    for (int j = beg + (int)threadIdx.x; j < end; j += 512) {
        unsigned p = binned[j];
        int dl = (int)(p & 511u);
        int pos = pbeg + pfx[dl] + atomicAdd(&hist[dl], 1);
        ssrc[pos] = (int)(p >> NB_SHIFT);
    }
    __syncthreads();

    // fill pad slots of own node with dummy src = n (zero row)
    if (node < n) {
        int base = pbeg + myexcl;
        for (int k = mydeg; k < mypc; ++k) ssrc[base + k] = n;
    }
}

// ---------------- weight pre-transpose + zero-row init ----------------
__global__ __launch_bounds__(256) void transpose_w_kernel(
        const float* __restrict__ W0, const float* __restrict__ W1,
        const float* __restrict__ W2, unsigned short* __restrict__ Wt) {
    int i = blockIdx.x * 256 + threadIdx.x;     // 0 .. 3*16384-1
    int w = i >> 14;
    int r = i & 16383;
    int k = r >> 7, c = r & 127;
    const float* W = (w == 0) ? W0 : ((w == 1) ? W1 : W2);
    Wt[(size_t)w * 16384 + c * 128 + k] = bf16_of(W[r]);
}

// zero feature row N in all three state buffers (dummy-edge target)
__global__ void zero_rows_kernel(unsigned short* __restrict__ Xb,
                                 unsigned short* __restrict__ U0,
                                 unsigned short* __restrict__ U1, int n) {
    int t = threadIdx.x;
    if (t >= 48) return;
    unsigned short* base = (t < 16) ? Xb : ((t < 32) ? U0 : U1);
    uint4v z = {0u, 0u, 0u, 0u};
    *((uint4v*)(base + (size_t)n * 128) + (t & 15)) = z;
}

// stage a 128x128 bf16 W^T (row-major, row = 128 shorts) into LDS with LDW=136
__device__ __forceinline__ void stage_w(unsigned short* __restrict__ sW,
                                        const unsigned short* __restrict__ Wt) {
    #pragma unroll
    for (int i = threadIdx.x; i < 128 * 16; i += 256) {
        int c = i >> 4, q = i & 15;
        *(uint4v*)(sW + c * 136 + q * 8) = *(const uint4v*)(Wt + c * 128 + q * 8);
    }
}

// ---------------- MFMA GEMM 1: [nrows x 128] fp32 @ W_in -> bf16 ------------
// W staged in LDS (straight copy of pre-transposed bf16), B-frags ds_read_b128.
__global__ __launch_bounds__(256) void gemm1_kernel(
        const float* __restrict__ Ap, const unsigned short* __restrict__ Wt,
        const float* __restrict__ bias, unsigned short* __restrict__ outp, int nrows) {
    constexpr int LDW = 136;
    __shared__ unsigned short sW[128 * LDW];   // 34816 B

    stage_w(sW, Wt);
    __syncthreads();

    const int wave = threadIdx.x >> 6;
    const int lane = threadIdx.x & 63;
    const int lhi = lane >> 4;
    const int llo = lane & 15;

    const int rbase = blockIdx.x * 128 + wave * 32;

    // preload + convert all A fragments (16 independent global loads)
    short8 af[2][4];
    #pragma unroll
    for (int rt = 0; rt < 2; ++rt) {
        int r = rbase + rt * 16 + llo;
        bool ok = r < nrows;
        const float* ap = Ap + (size_t)r * 128 + lhi * 8;
        #pragma unroll
        for (int ks = 0; ks < 4; ++ks) {
            float4 f0 = ok ? *(const float4*)(ap + ks * 32) : make_float4(0.f, 0.f, 0.f, 0.f);
            float4 f1 = ok ? *(const float4*)(ap + ks * 32 + 4) : make_float4(0.f, 0.f, 0.f, 0.f);
            union { unsigned u[4]; short8 s; } cvt;
            cvt.u[0] = pack_bf2(f0.x, f0.y);
            cvt.u[1] = pack_bf2(f0.z, f0.w);
            cvt.u[2] = pack_bf2(f1.x, f1.y);
            cvt.u[3] = pack_bf2(f1.z, f1.w);
            af[rt][ks] = cvt.s;
        }
    }

    f32x4 acc[2][8] = {};
    #pragma unroll
    for (int ks = 0; ks < 4; ++ks) {
        const int k0 = ks * 32 + lhi * 8;
        #pragma unroll
        for (int ct = 0; ct < 8; ++ct) {
            short8 bf = *(const short8*)(sW + (size_t)(ct * 16 + llo) * LDW + k0);
            acc[0][ct] = __builtin_amdgcn_mfma_f32_16x16x32_bf16(af[0][ks], bf, acc[0][ct], 0, 0, 0);
            acc[1][ct] = __builtin_amdgcn_mfma_f32_16x16x32_bf16(af[1][ks], bf, acc[1][ct], 0, 0, 0);
        }
    }

    float bv[8];
    #pragma unroll
    for (int ct = 0; ct < 8; ++ct) bv[ct] = bias[ct * 16 + llo];

    #pragma unroll
    for (int rt = 0; rt < 2; ++rt) {
        int rb = rbase + rt * 16 + lhi * 4;
        #pragma unroll
        for (int reg = 0; reg < 4; ++reg) {
            int r = rb + reg;
            if (r >= nrows) continue;
            unsigned short* orow = outp + (size_t)r * 128;
            #pragma unroll
            for (int ct = 0; ct < 8; ++ct) {
                float v = silu_f(acc[rt][ct][reg] + bv[ct]);
                orow[ct * 16 + llo] = bf16_of(v);
            }
        }
    }
}

// ---------------- fused GEMM2+GEMM3: out = silu(U@W1+b1) @ W2 + b2 ----------
// 64-row tile. sW (34.8 KB) staged with W1t for phase 1, re-staged with W2t
// for phase 2; sX (17.4 KB) holds the silu tile. 52.2 KB LDS -> 3 blocks/CU.
// x2 and both W reads never touch HBM/L2 in the inner loops.
__global__ __launch_bounds__(256) void gemm23_fused_kernel(
        const unsigned short* __restrict__ U,
        const unsigned short* __restrict__ W1t, const float* __restrict__ b1,
        const unsigned short* __restrict__ W2t, const float* __restrict__ b2,
        float* __restrict__ out, int nrows) {
    constexpr int LDW = 136;
    constexpr int LDX = 136;
    __shared__ unsigned short sW[128 * LDW];   // 34816 B
    __shared__ unsigned short sX[64 * LDX];    // 17408 B

    const int wave = threadIdx.x >> 6;
    const int lane = threadIdx.x & 63;
    const int lhi = lane >> 4;
    const int llo = lane & 15;

    const int rbase = blockIdx.x * 64 + wave * 16;
    const int lbase = wave * 16;

    stage_w(sW, W1t);

    // A-frags for phase 1 (4 independent global loads, issued before sync)
    int r = rbase + llo;
    bool ok = r < nrows;
    short8 af[4];
    #pragma unroll
    for (int ks = 0; ks < 4; ++ks)
        af[ks] = ok ? *(const short8*)(U + (size_t)r * 128 + ks * 32 + lhi * 8)
                    : short8{0, 0, 0, 0, 0, 0, 0, 0};
    __syncthreads();

    // ---- phase 1: sX = silu(U_tile @ W1 + b1) ----
    {
        f32x4 acc[8] = {};
        #pragma unroll
        for (int ks = 0; ks < 4; ++ks) {
            const int k0 = ks * 32 + lhi * 8;
            #pragma unroll
            for (int ct = 0; ct < 8; ++ct) {
                short8 bf = *(const short8*)(sW + (size_t)(ct * 16 + llo) * LDW + k0);
                acc[ct] = __builtin_amdgcn_mfma_f32_16x16x32_bf16(af[ks], bf, acc[ct], 0, 0, 0);
            }
        }
        float bv[8];
        #pragma unroll
        for (int ct = 0; ct < 8; ++ct) bv[ct] = b1[ct * 16 + llo];
        #pragma unroll
        for (int reg = 0; reg < 4; ++reg) {
            unsigned short* srow = sX + (size_t)(lbase + lhi * 4 + reg) * LDX;
            #pragma unroll
            for (int ct = 0; ct < 8; ++ct) {
                float v = silu_f(acc[ct][reg] + bv[ct]);
                srow[ct * 16 + llo] = bf16_of(v);
            }
        }
    }
    __syncthreads();          // all sW reads + sX writes complete

    stage_w(sW, W2t);         // overwrite with W2t
    __syncthreads();

    // ---- phase 2: out = sX @ W2 + b2 ----
    #pragma unroll
    for (int ks = 0; ks < 4; ++ks)
        af[ks] = *(const short8*)(sX + (size_t)(lbase + llo) * LDX + ks * 32 + lhi * 8);

    f32x4 acc[8] = {};
    #pragma unroll
    for (int ks = 0; ks < 4; ++ks) {
        const int k0 = ks * 32 + lhi * 8;
        #pragma unroll
        for (int ct = 0; ct < 8; ++ct) {
            short8 bf = *(const short8*)(sW + (size_t)(ct * 16 + llo) * LDW + k0);
            acc[ct] = __builtin_amdgcn_mfma_f32_16x16x32_bf16(af[ks], bf, acc[ct], 0, 0, 0);
        }
    }
    float bv[8];
    #pragma unroll
    for (int ct = 0; ct < 8; ++ct) bv[ct] = b2[ct * 16 + llo];
    #pragma unroll
    for (int reg = 0; reg < 4; ++reg) {
        int rr = rbase + lhi * 4 + reg;
        if (rr >= nrows) continue;
        float* orow = out + (size_t)rr * 128;
        #pragma unroll
        for (int ct = 0; ct < 8; ++ct)
            orow[ct * 16 + llo] = acc[ct][reg] + bv[ct];
    }
}

// ---------------- Horner diffusion step, row-major bf16, padded CSR ---------

#define ACC8(v)                                          \
    do {                                                 \
        a0 += __uint_as_float((v).x << 16);              \
        a1 += __uint_as_float((v).x & 0xffff0000u);      \
        a2 += __uint_as_float((v).y << 16);              \
        a3 += __uint_as_float((v).y & 0xffff0000u);      \
        a4 += __uint_as_float((v).z << 16);              \
        a5 += __uint_as_float((v).z & 0xffff0000u);      \
        a6 += __uint_as_float((v).w << 16);              \
        a7 += __uint_as_float((v).w & 0xffff0000u);      \
    } while (0)

__global__ __launch_bounds__(256) void horner_bf_kernel(
        const uint4v* __restrict__ u, const uint4v* __restrict__ xb,
        uint4v* __restrict__ u_next,
        const int* __restrict__ row_start, const int* __restrict__ degv,
        const int* __restrict__ ssrc,
        float inv_i, int nrows) {
    const int lt = threadIdx.x & 15;                 // lane within row group
    const int row = blockIdx.x * 16 + (threadIdx.x >> 4);
    if (row >= nrows) return;

    const int beg = row_start[row];
    const int deg = degv[row];
    const int pend = beg + ((deg + 7) & ~7);

    float a0 = 0.f, a1 = 0.f, a2 = 0.f, a3 = 0.f,
          a4 = 0.f, a5 = 0.f, a6 = 0.f, a7 = 0.f;

    for (int j = beg; j < pend; j += 8) {
        int4 sA = *(const int4*)(ssrc + j);
        int4 sB = *(const int4*)(ssrc + j + 4);
        uint4v t0 = u[(size_t)sA.x * 16 + lt];
        uint4v t1 = u[(size_t)sA.y * 16 + lt];
        uint4v t2 = u[(size_t)sA.z * 16 + lt];
        uint4v t3 = u[(size_t)sA.w * 16 + lt];
        uint4v t4 = u[(size_t)sB.x * 16 + lt];
        uint4v t5 = u[(size_t)sB.y * 16 + lt];
        uint4v t6 = u[(size_t)sB.z * 16 + lt];
        uint4v t7 = u[(size_t)sB.w * 16 + lt];
        ACC8(t0); ACC8(t1); ACC8(t2); ACC8(t3);
        ACC8(t4); ACC8(t5); ACC8(t6); ACC8(t7);
    }

    const float scale = inv_i / (float)(deg > 1 ? deg : 1);
    const size_t o = (size_t)row * 16 + lt;
    uint4v xv = xb[o];
    float r0 = fmaf(a0, scale, __uint_as_float(xv.x << 16));
    float r1 = fmaf(a1, scale, __uint_as_float(xv.x & 0xffff0000u));
    float r2 = fmaf(a2, scale, __uint_as_float(xv.y << 16));
    float r3 = fmaf(a3, scale, __uint_as_float(xv.y & 0xffff0000u));
    float r4 = fmaf(a4, scale, __uint_as_float(xv.z << 16));
    float r5 = fmaf(a5, scale, __uint_as_float(xv.z & 0xffff0000u));
    float r6 = fmaf(a6, scale, __uint_as_float(xv.w << 16));
    float r7 = fmaf(a7, scale, __uint_as_float(xv.w & 0xffff0000u));
    uint4v ov;
    ov.x = pack_bf2(r0, r1);
    ov.y = pack_bf2(r2, r3);
    ov.z = pack_bf2(r4, r5);
    ov.w = pack_bf2(r6, r7);
    u_next[o] = ov;
}

// ---------------- launch ----------------

extern "C" void kernel_launch(void* const* d_in, const int* in_sizes, int n_in,
                              void* d_out, int out_size, void* d_ws, size_t ws_size,
                              hipStream_t stream) {
    const float* h      = (const float*)d_in[0];
    const int*   eidx   = (const int*)d_in[1];
    const float* W_in   = (const float*)d_in[2];
    const float* b_in   = (const float*)d_in[3];
    const float* W1     = (const float*)d_in[4];
    const float* b1     = (const float*)d_in[5];
    const float* W2     = (const float*)d_in[6];
    const float* b2     = (const float*)d_in[7];
    float* out = (float*)d_out;

    const int N = in_sizes[0] / D;      // 100000
    const int E = in_sizes[1] / 2;      // 1600000
    const int NB = (N + (1 << NB_SHIFT) - 1) >> NB_SHIFT;   // 196 buckets

    const int* e_src = eidx;
    const int* e_dst = eidx + E;

    const size_t rowsz = (size_t)(N + 1) * 128;   // +1 zero row for dummy edges

    // workspace layout
    unsigned short* Xb = (unsigned short*)d_ws;         // (N+1)*128 shorts
    unsigned short* U0 = Xb + rowsz;                    // (N+1)*128 shorts
    unsigned short* U1 = U0 + rowsz;                    // (N+1)*128 shorts
    unsigned short* Wt = U1 + rowsz;                    // 3*16384 shorts
    unsigned* binned   = (unsigned*)(Wt + 3 * 16384);   // NB*BCAP
    int* ssrc        = (int*)(binned + (size_t)NB * BCAP);  // NB*BCAPP
    int* row_start   = ssrc + (size_t)NB * BCAPP;       // N
    int* degv        = row_start + N;                   // N
    int* bin_cur     = degv + N;                        // 256

    zero_rows_kernel<<<1, 64, 0, stream>>>(Xb, U0, U1, N);
    init_cur_kernel<<<1, 256, 0, stream>>>(bin_cur, NB);

    const int eb = (E + 256 * CPT - 1) / (256 * CPT);
    bin_edges_kernel<<<eb, 256, 0, stream>>>(e_src, e_dst, bin_cur, binned, E, NB);
    bucket_csr_kernel<<<NB, 512, 0, stream>>>(binned, bin_cur, row_start, degv,
                                              ssrc, N, E, NB);

    // weight pre-transpose (bf16 W^T for all three GEMMs)
    transpose_w_kernel<<<192, 256, 0, stream>>>(W_in, W1, W2, Wt);

    const int gb = (N + 127) / 128;
    // Xb = bf16(silu(h @ W_in + b_in))
    gemm1_kernel<<<gb, 256, 0, stream>>>(h, Wt, b_in, Xb, N);

    // Horner: u = x; for i = K..1: u = x + (A u)/i   (bf16 state)
    const int db = (N + 15) / 16;
    const uint4v* Xv = (const uint4v*)Xb;
    uint4v* U0v = (uint4v*)U0;
    uint4v* U1v = (uint4v*)U1;
    horner_bf_kernel<<<db, 256, 0, stream>>>(Xv, Xv, U0v, row_start, degv, ssrc, 1.0f / 6.0f, N);
    horner_bf_kernel<<<db, 256, 0, stream>>>(U0v, Xv, U1v, row_start, degv, ssrc, 1.0f / 5.0f, N);
    horner_bf_kernel<<<db, 256, 0, stream>>>(U1v, Xv, U0v, row_start, degv, ssrc, 1.0f / 4.0f, N);
    horner_bf_kernel<<<db, 256, 0, stream>>>(U0v, Xv, U1v, row_start, degv, ssrc, 1.0f / 3.0f, N);
    horner_bf_kernel<<<db, 256, 0, stream>>>(U1v, Xv, U0v, row_start, degv, ssrc, 1.0f / 2.0f, N);
    horner_bf_kernel<<<db, 256, 0, stream>>>(U0v, Xv, U1v, row_start, degv, ssrc, 1.0f, N);
    // final diffusion result: U1 (bf16)

    // out = silu(U1 @ W1 + b1) @ W2 + b2   (fused, x2 + W stay in LDS)
    const int gb2 = (N + 63) / 64;
    gemm23_fused_kernel<<<gb2, 256, 0, stream>>>(U1, Wt + 16384, b1,
                                                 Wt + 2 * 16384, b2, out, N);
}